// Round 2
// baseline (1686.496 us; speedup 1.0000x reference)
//
#include <hip/hip_runtime.h>

#define EPSV 1e-5f
#define CLS_SZ (32768*6)
// swizzled [ch][row] LDS layout: conflict-free for both row-lane reads and writes
#define SW(k,r) (((k)<<7) + ((r) ^ ((k)&31)))

__device__ __forceinline__ int rfl(int x) { return __builtin_amdgcn_readfirstlane(x); }

// acc[NC] += sum_k A[k][row] * W[k][col0+c]; W read wave-uniformly (scalar path)
template<int NC, int LDW>
__device__ __forceinline__ void gemm128(const float* __restrict__ A,
                                        const float* __restrict__ Wp,  // = W + col0
                                        int row, float* acc)
{
  #pragma unroll 4
  for (int k = 0; k < 128; ++k) {
    float x = A[SW(k, row)];
    const float4* wr = reinterpret_cast<const float4*>(Wp + (size_t)k * LDW);
    #pragma unroll
    for (int c4 = 0; c4 < NC/4; ++c4) {
      float4 w = wr[c4];
      acc[4*c4+0] = fmaf(w.x, x, acc[4*c4+0]);
      acc[4*c4+1] = fmaf(w.y, x, acc[4*c4+1]);
      acc[4*c4+2] = fmaf(w.z, x, acc[4*c4+2]);
      acc[4*c4+3] = fmaf(w.w, x, acc[4*c4+3]);
    }
  }
}

// GroupNorm(1,128) stats; 128 rows, 4 col-quarter partials per row
__device__ __forceinline__ void gn_stats(const float* acc, float* PS1, float* PS2,
                                         float* MEAN, float* RSTD, int row, int q, int tid)
{
  float s = 0.f, ss = 0.f;
  #pragma unroll
  for (int c = 0; c < 32; ++c) { float v = acc[c]; s += v; ss += v*v; }
  PS1[row*5 + q] = s;
  PS2[row*5 + q] = ss;
  __syncthreads();
  if (tid < 128) {
    float a = 0.f, b = 0.f;
    #pragma unroll
    for (int j = 0; j < 4; ++j) { a += PS1[tid*5 + j]; b += PS2[tid*5 + j]; }
    float mu = a * 0.0078125f;
    float var = b * 0.0078125f - mu*mu;
    MEAN[tid] = mu;
    RSTD[tid] = rsqrtf(var + EPSV);
  }
  __syncthreads();
}

// ---------------- Kernel A: per-mode pred heads -> unsorted reg ----------------
__global__ void __launch_bounds__(512) pred_kernel(
    const float* __restrict__ actors, const float* __restrict__ ctrs,
    const float* __restrict__ W1, const float* __restrict__ g1v, const float* __restrict__ b1v,
    const float* __restrict__ W2, const float* __restrict__ g2v, const float* __restrict__ b2v,
    const float* __restrict__ Wo, const float* __restrict__ bov,
    float* __restrict__ out_reg)
{
  __shared__ float ACTORS[128*128];
  __shared__ float ACT[128*128];
  __shared__ float PS1[128*5], PS2[128*5], MEAN[128], RSTD[128];

  const int tid  = threadIdx.x;
  const int lane = tid & 63;
  const int wid  = rfl(tid >> 6);
  const int h = wid >> 2, q = wid & 3;
  const int row  = h*64 + lane;
  const int col0 = q*32;
  const int m  = blockIdx.y;
  const int n0 = blockIdx.x * 128;

  // stage actors tile: coalesced global read, conflict-free swizzled LDS write
  for (int i = tid; i < 16384; i += 512) {
    int ch = i & 127, r = i >> 7;
    ACTORS[SW(ch, r)] = actors[(size_t)(n0 + r)*128 + ch];
  }
  __syncthreads();

  float acc[32];

  // layer 1: relu(GN(actors @ W1))
  #pragma unroll
  for (int c = 0; c < 32; ++c) acc[c] = 0.f;
  gemm128<32,128>(ACTORS, W1 + (size_t)m*16384 + col0, row, acc);
  gn_stats(acc, PS1, PS2, MEAN, RSTD, row, q, tid);
  {
    float mu = MEAN[row], rs = RSTD[row];
    #pragma unroll
    for (int c = 0; c < 32; ++c) {
      int ch = col0 + c;
      float v = (acc[c] - mu) * rs * g1v[m*128 + ch] + b1v[m*128 + ch];
      ACT[SW(ch, row)] = fmaxf(v, 0.f);
    }
  }
  __syncthreads();

  // layer 2: relu(GN(h1 @ W2) + actors)
  #pragma unroll
  for (int c = 0; c < 32; ++c) acc[c] = 0.f;
  gemm128<32,128>(ACT, W2 + (size_t)m*16384 + col0, row, acc);
  gn_stats(acc, PS1, PS2, MEAN, RSTD, row, q, tid);
  {
    float mu = MEAN[row], rs = RSTD[row];
    #pragma unroll
    for (int c = 0; c < 32; ++c) {
      int ch = col0 + c;
      float v = (acc[c] - mu) * rs * g2v[m*128 + ch] + b2v[m*128 + ch];
      v += ACTORS[SW(ch, row)];
      ACT[SW(ch, row)] = fmaxf(v, 0.f);
    }
  }
  __syncthreads();

  // output layer: h @ Wo + bo + ctr
  float acco[16];
  #pragma unroll
  for (int c = 0; c < 16; ++c) acco[c] = 0.f;
  {
    const float* WoP = Wo + (size_t)m*7680 + q*16;
    if (q < 3) gemm128<16,60>(ACT, WoP, row, acco);
    else       gemm128<12,60>(ACT, WoP, row, acco);
  }
  {
    int n = n0 + row;
    float cx = ctrs[2*n], cy = ctrs[2*n+1];
    int ncv = (q < 3) ? 4 : 3;
    for (int c4 = 0; c4 < ncv; ++c4) {
      int j = q*16 + 4*c4;
      float4 v;
      v.x = acco[4*c4+0] + bov[m*60 + j + 0] + cx;
      v.y = acco[4*c4+1] + bov[m*60 + j + 1] + cy;
      v.z = acco[4*c4+2] + bov[m*60 + j + 2] + cx;
      v.w = acco[4*c4+3] + bov[m*60 + j + 3] + cy;
      *reinterpret_cast<float4*>(out_reg + (size_t)n*360 + m*60 + j) = v;
    }
  }
}

// ---------------- Kernel B: AttDest + cls head -> unsorted cls ----------------
__global__ void __launch_bounds__(512) att_cls_kernel(
    const float* __restrict__ actors, const float* __restrict__ ctrs,
    const float* __restrict__ dW1, const float* __restrict__ db1,
    const float* __restrict__ dW2, const float* __restrict__ dg2, const float* __restrict__ db2,
    const float* __restrict__ aW, const float* __restrict__ aG, const float* __restrict__ aB,
    const float* __restrict__ cW1, const float* __restrict__ cg1, const float* __restrict__ cb1,
    const float* __restrict__ cW2, const float* __restrict__ cg2, const float* __restrict__ cb2,
    const float* __restrict__ cWo, const float* __restrict__ cbo,
    const float* __restrict__ reg, float* __restrict__ cls_out)
{
  __shared__ float ACT[128*128];
  __shared__ float FEATS[128*128];
  __shared__ float PS1[128*5], PS2[128*5], MEAN[128], RSTD[128];
  __shared__ float D0x[128], D0y[128];

  const int tid  = threadIdx.x;
  const int lane = tid & 63;
  const int wid  = rfl(tid >> 6);
  const int h = wid >> 2, q = wid & 3;
  const int row  = h*64 + lane;
  const int col0 = q*32;
  const int r0 = blockIdx.x * 128;

  // phase 0: dist0 = ctr - reg_last
  if (tid < 128) {
    int rg = r0 + tid;
    int n = rg / 6, mm = rg - 6*n;
    size_t base = (size_t)n*360 + mm*60;
    D0x[tid] = ctrs[2*n]     - reg[base + 58];
    D0y[tid] = ctrs[2*n + 1] - reg[base + 59];
  }
  __syncthreads();

  // phase 1: dist1 = relu(dist0 @ dW1 + db1) -> ACT ; stage agts -> FEATS
  {
    float dx = D0x[row], dy = D0y[row];
    #pragma unroll
    for (int c = 0; c < 32; ++c) {
      int ch = col0 + c;
      float v = fmaf(dx, dW1[ch], fmaf(dy, dW1[128 + ch], db1[ch]));
      ACT[SW(ch, row)] = fmaxf(v, 0.f);
    }
  }
  for (int i = tid; i < 16384; i += 512) {
    int ch = i & 127, r = i >> 7;
    int n = (r0 + r) / 6;
    FEATS[SW(ch, r)] = actors[(size_t)n*128 + ch];
  }
  __syncthreads();

  float acc[32];

  // phase 2: dist2 = relu(GN(dist1 @ dW2)) -> ACT (in place)
  #pragma unroll
  for (int c = 0; c < 32; ++c) acc[c] = 0.f;
  gemm128<32,128>(ACT, dW2 + col0, row, acc);
  gn_stats(acc, PS1, PS2, MEAN, RSTD, row, q, tid);
  {
    float mu = MEAN[row], rs = RSTD[row];
    #pragma unroll
    for (int c = 0; c < 32; ++c) {
      int ch = col0 + c;
      float v = (acc[c] - mu) * rs * dg2[ch] + db2[ch];
      ACT[SW(ch, row)] = fmaxf(v, 0.f);
    }
  }
  __syncthreads();

  // phase 3: feats = relu(GN(dist2 @ aW_lo + agts @ aW_hi)) -> ACT and FEATS
  #pragma unroll
  for (int c = 0; c < 32; ++c) acc[c] = 0.f;
  gemm128<32,128>(ACT,   aW + col0,            row, acc);
  gemm128<32,128>(FEATS, aW + 128*128 + col0,  row, acc);
  gn_stats(acc, PS1, PS2, MEAN, RSTD, row, q, tid);
  {
    float mu = MEAN[row], rs = RSTD[row];
    #pragma unroll
    for (int c = 0; c < 32; ++c) {
      int ch = col0 + c;
      float v = (acc[c] - mu) * rs * aG[ch] + aB[ch];
      v = fmaxf(v, 0.f);
      ACT[SW(ch, row)]   = v;
      FEATS[SW(ch, row)] = v;
    }
  }
  __syncthreads();

  // phase 4: c1 = relu(GN(feats @ cls_W1)) -> ACT
  #pragma unroll
  for (int c = 0; c < 32; ++c) acc[c] = 0.f;
  gemm128<32,128>(ACT, cW1 + col0, row, acc);
  gn_stats(acc, PS1, PS2, MEAN, RSTD, row, q, tid);
  {
    float mu = MEAN[row], rs = RSTD[row];
    #pragma unroll
    for (int c = 0; c < 32; ++c) {
      int ch = col0 + c;
      float v = (acc[c] - mu) * rs * cg1[ch] + cb1[ch];
      ACT[SW(ch, row)] = fmaxf(v, 0.f);
    }
  }
  __syncthreads();

  // phase 5: c2 = GN(c1 @ cls_W2); c = relu(c2 + feats); cls = c @ cls_Wo + bo
  #pragma unroll
  for (int c = 0; c < 32; ++c) acc[c] = 0.f;
  gemm128<32,128>(ACT, cW2 + col0, row, acc);
  gn_stats(acc, PS1, PS2, MEAN, RSTD, row, q, tid);
  {
    float mu = MEAN[row], rs = RSTD[row];
    float p = 0.f;
    #pragma unroll
    for (int c = 0; c < 32; ++c) {
      int ch = col0 + c;
      float v = (acc[c] - mu) * rs * cg2[ch] + cb2[ch];
      v = fmaxf(v + FEATS[SW(ch, row)], 0.f);
      p = fmaf(v, cWo[ch], p);
    }
    PS1[row*5 + q] = p;
  }
  __syncthreads();
  if (tid < 128) {
    float s = 0.f;
    #pragma unroll
    for (int j = 0; j < 4; ++j) s += PS1[tid*5 + j];
    cls_out[r0 + tid] = s + cbo[0];
  }
}

// ---------------- Kernel C: per-actor stable descending sort + permute ----------------
__global__ void __launch_bounds__(256) sort_kernel(float* __restrict__ out)
{
  __shared__ float RL[64*360];
  __shared__ float CL[64*6];
  __shared__ float CS[64*6];
  __shared__ int   ORD[64*6];

  const int tid = threadIdx.x;
  const int n0 = blockIdx.x * 64;
  float* regp = out + CLS_SZ;

  for (int i = tid; i < 64*360; i += 256) RL[i] = regp[(size_t)n0*360 + i];
  for (int i = tid; i < 384; i += 256)    CL[i] = out[n0*6 + i];
  __syncthreads();

  if (tid < 64) {
    float v[6];
    #pragma unroll
    for (int m2 = 0; m2 < 6; ++m2) v[m2] = CL[tid*6 + m2];
    int used = 0;
    for (int j = 0; j < 6; ++j) {
      int best = -1; float bv = 0.f;
      for (int m2 = 0; m2 < 6; ++m2) {
        if (used & (1 << m2)) continue;
        if (best < 0 || v[m2] > bv) { best = m2; bv = v[m2]; }  // stable: strict >
      }
      used |= (1 << best);
      ORD[tid*6 + j] = best;
      CS[tid*6 + j] = bv;
    }
  }
  __syncthreads();

  for (int i = tid; i < 384; i += 256) out[n0*6 + i] = CS[i];
  for (int i = tid; i < 64*360; i += 256) {
    int rl = i / 360, rem = i - rl*360;
    int slot = rem / 60, j = rem - slot*60;
    out[CLS_SZ + (size_t)n0*360 + i] = RL[rl*360 + ORD[rl*6 + slot]*60 + j];
  }
}

extern "C" void kernel_launch(void* const* d_in, const int* in_sizes, int n_in,
                              void* d_out, int out_size, void* d_ws, size_t ws_size,
                              hipStream_t stream)
{
  (void)in_sizes; (void)n_in; (void)out_size; (void)d_ws; (void)ws_size;
  const float* actors = (const float*)d_in[0];
  const float* ctrs   = (const float*)d_in[1];
  // d_in[2] = actor_idcs (identity partition; unused by the math)
  const float* pW1 = (const float*)d_in[3];
  const float* pg1 = (const float*)d_in[4];
  const float* pb1 = (const float*)d_in[5];
  const float* pW2 = (const float*)d_in[6];
  const float* pg2 = (const float*)d_in[7];
  const float* pb2 = (const float*)d_in[8];
  const float* pWo = (const float*)d_in[9];
  const float* pbo = (const float*)d_in[10];
  const float* cW1 = (const float*)d_in[11];
  const float* cg1 = (const float*)d_in[12];
  const float* cb1 = (const float*)d_in[13];
  const float* cW2 = (const float*)d_in[14];
  const float* cg2 = (const float*)d_in[15];
  const float* cb2 = (const float*)d_in[16];
  const float* cWo = (const float*)d_in[17];
  const float* cbo = (const float*)d_in[18];
  const float* dW1 = (const float*)d_in[19];
  const float* db1 = (const float*)d_in[20];
  const float* dW2 = (const float*)d_in[21];
  const float* dg2 = (const float*)d_in[22];
  const float* db2 = (const float*)d_in[23];
  const float* aW  = (const float*)d_in[24];
  const float* aG  = (const float*)d_in[25];
  const float* aB  = (const float*)d_in[26];

  float* out = (float*)d_out;
  float* out_reg = out + CLS_SZ;

  dim3 gA(256, 6);
  pred_kernel<<<gA, 512, 0, stream>>>(actors, ctrs, pW1, pg1, pb1, pW2, pg2, pb2,
                                      pWo, pbo, out_reg);
  att_cls_kernel<<<1536, 512, 0, stream>>>(actors, ctrs,
                                           dW1, db1, dW2, dg2, db2,
                                           aW, aG, aB,
                                           cW1, cg1, cb1, cW2, cg2, cb2, cWo, cbo,
                                           out_reg, out);
  sort_kernel<<<512, 256, 0, stream>>>(out);
}

// Round 3
// 768.636 us; speedup vs baseline: 2.1941x; 2.1941x over previous
//
#include <hip/hip_runtime.h>

#define EPSV 1e-5f
#define CLS_SZ (32768*6)

// swizzled activation LDS word index for [k][r], 64 rows/block.
// XOR on word bits 2-5 keeps 16B alignment for b128 and spreads banks.
#define AIDX(k,r) (((k)<<6) + ((r) ^ (((k)&15)<<2)))

__device__ __forceinline__ float4 ld4(const float* p) { return *reinterpret_cast<const float4*>(p); }
__device__ __forceinline__ void st4(float* p, float4 v) { *reinterpret_cast<float4*>(p) = v; }

__device__ __forceinline__ void fma48(float4 x, float4 wl, float4 wh, float acc[4][8]) {
  float av[4] = {x.x, x.y, x.z, x.w};
  float wv[8] = {wl.x, wl.y, wl.z, wl.w, wh.x, wh.y, wh.z, wh.w};
  #pragma unroll
  for (int r = 0; r < 4; ++r)
    #pragma unroll
    for (int c = 0; c < 8; ++c)
      acc[r][c] = fmaf(av[r], wv[c], acc[r][c]);
}

// X: swizzled [128][64] LDS activations; Wg: global [128][128] row-major.
// W streamed through WB0/WB1 (1024 floats each), double-buffered, prefetch 2 ahead.
__device__ __forceinline__ void gemm128c(const float* __restrict__ X,
                                         const float* __restrict__ Wg,
                                         float* __restrict__ WB0, float* __restrict__ WB1,
                                         float acc[4][8], int ag4, int jg4, int tid)
{
  float4 rA = ld4(Wg + tid*4);
  float4 rB = ld4(Wg + 1024 + tid*4);
  __syncthreads();                 // prior phase done with WB/X
  st4(WB0 + tid*4, rA);
  st4(WB1 + tid*4, rB);
  __syncthreads();
  #pragma unroll 1
  for (int c = 0; c < 16; ++c) {
    float4 rN;
    const bool pf = (c + 2 < 16);
    if (pf) rN = ld4(Wg + (c+2)*1024 + tid*4);
    const float* WB = (c & 1) ? WB1 : WB0;
    #pragma unroll
    for (int kk = 0; kk < 8; ++kk) {
      int k = c*8 + kk;
      float4 x  = ld4(X + ((k<<6) + (ag4 ^ ((k&15)<<2))));
      float4 wl = ld4(WB + (kk<<7) + jg4);
      float4 wh = ld4(WB + (kk<<7) + 64 + jg4);
      fma48(x, wl, wh, acc);
    }
    __syncthreads();               // everyone done reading WB[c&1]
    if (pf) st4(((c & 1) ? WB1 : WB0) + tid*4, rN);
  }
}

// Output-layer gemm: Wg global [128][60], staged padded to [8][64] chunks.
__device__ __forceinline__ void gemm128wo(const float* __restrict__ X,
                                          const float* __restrict__ Wg,
                                          float* __restrict__ WB0, float* __restrict__ WB1,
                                          float acc[4][4], int ag4, int jg4, int tid)
{
  const bool act = tid < 120;
  const int row = tid / 15, col = (tid % 15) * 4;
  float4 rA, rB;
  if (act) { rA = ld4(Wg + row*60 + col); rB = ld4(Wg + 480 + row*60 + col); }
  __syncthreads();
  if (act) { st4(WB0 + (row<<6) + col, rA); st4(WB1 + (row<<6) + col, rB); }
  __syncthreads();
  #pragma unroll 1
  for (int c = 0; c < 16; ++c) {
    float4 rN;
    const bool pf = act && (c + 2 < 16);
    if (pf) rN = ld4(Wg + (c+2)*480 + row*60 + col);
    const float* WB = (c & 1) ? WB1 : WB0;
    #pragma unroll
    for (int kk = 0; kk < 8; ++kk) {
      int k = c*8 + kk;
      float4 x = ld4(X + ((k<<6) + (ag4 ^ ((k&15)<<2))));
      float4 w = ld4(WB + (kk<<6) + jg4);
      float av[4] = {x.x, x.y, x.z, x.w};
      float wv[4] = {w.x, w.y, w.z, w.w};
      #pragma unroll
      for (int r = 0; r < 4; ++r)
        #pragma unroll
        for (int cc = 0; cc < 4; ++cc)
          acc[r][cc] = fmaf(av[r], wv[cc], acc[r][cc]);
    }
    __syncthreads();
    if (pf) st4(((c & 1) ? WB1 : WB0) + (row<<6) + col, rN);
  }
}

// GroupNorm(1,128) stats: quad shfl pre-reduce, then 4 partials/row in LDS.
__device__ __forceinline__ void gn_reduce(const float acc[4][8], float* PS1, float* PS2,
                                          float* MEAN, float* RSTD, int ag4, int jg, int tid)
{
  #pragma unroll
  for (int r = 0; r < 4; ++r) {
    float s = 0.f, q = 0.f;
    #pragma unroll
    for (int c = 0; c < 8; ++c) { float v = acc[r][c]; s += v; q += v*v; }
    s += __shfl_xor(s, 1, 64); q += __shfl_xor(q, 1, 64);
    s += __shfl_xor(s, 2, 64); q += __shfl_xor(q, 2, 64);
    PS1[(ag4+r)*5 + (jg>>2)] = s;
    PS2[(ag4+r)*5 + (jg>>2)] = q;
  }
  __syncthreads();
  if (tid < 64) {
    float a = 0.f, b = 0.f;
    #pragma unroll
    for (int j = 0; j < 4; ++j) { a += PS1[tid*5 + j]; b += PS2[tid*5 + j]; }
    float mu = a * 0.0078125f;
    float var = b * 0.0078125f - mu*mu;
    MEAN[tid] = mu;
    RSTD[tid] = rsqrtf(var + EPSV);
  }
  __syncthreads();
}

// ---------------- Kernel A: per-mode pred heads -> unsorted reg ----------------
__global__ void __launch_bounds__(256) pred_kernel(
    const float* __restrict__ actors, const float* __restrict__ ctrs,
    const float* __restrict__ W1, const float* __restrict__ g1v, const float* __restrict__ b1v,
    const float* __restrict__ W2, const float* __restrict__ g2v, const float* __restrict__ b2v,
    const float* __restrict__ Wo, const float* __restrict__ bov,
    float* __restrict__ out_reg)
{
  __shared__ __align__(16) float ACTORS[8192];
  __shared__ __align__(16) float ACT[8192];
  __shared__ __align__(16) float WB0[1024], WB1[1024];
  __shared__ float PS1[320], PS2[320], MEAN[64], RSTD[64];

  const int tid = threadIdx.x;
  const int jg = tid & 15, ag = tid >> 4;
  const int jg4 = jg*4, ag4 = ag*4;
  const int m  = blockIdx.y;
  const int n0 = blockIdx.x * 64;

  // stage actors tile transposed+swizzled
  #pragma unroll
  for (int p = 0; p < 8; ++p) {
    int i = (p<<8) + tid;
    int r = i >> 5, c4 = (i & 31) << 2;
    float4 v = ld4(actors + (size_t)(n0 + r)*128 + c4);
    ACTORS[((c4+0)<<6) + (r ^ ((((c4+0))&15)<<2))] = v.x;
    ACTORS[((c4+1)<<6) + (r ^ ((((c4+1))&15)<<2))] = v.y;
    ACTORS[((c4+2)<<6) + (r ^ ((((c4+2))&15)<<2))] = v.z;
    ACTORS[((c4+3)<<6) + (r ^ ((((c4+3))&15)<<2))] = v.w;
  }

  float acc[4][8];
  #pragma unroll
  for (int r = 0; r < 4; ++r)
    #pragma unroll
    for (int c = 0; c < 8; ++c) acc[r][c] = 0.f;

  // layer 1: relu(GN(actors @ W1)) -> ACT
  gemm128c(ACTORS, W1 + (size_t)m*16384, WB0, WB1, acc, ag4, jg4, tid);
  gn_reduce(acc, PS1, PS2, MEAN, RSTD, ag4, jg, tid);
  {
    float mu[4], rs[4];
    #pragma unroll
    for (int r = 0; r < 4; ++r) { mu[r] = MEAN[ag4+r]; rs[r] = RSTD[ag4+r]; }
    #pragma unroll
    for (int c = 0; c < 8; ++c) {
      int ch = (c < 4) ? (jg4 + c) : (64 + jg4 + (c - 4));
      float g = g1v[m*128 + ch], b = b1v[m*128 + ch];
      float4 v;
      v.x = fmaxf((acc[0][c] - mu[0]) * rs[0] * g + b, 0.f);
      v.y = fmaxf((acc[1][c] - mu[1]) * rs[1] * g + b, 0.f);
      v.z = fmaxf((acc[2][c] - mu[2]) * rs[2] * g + b, 0.f);
      v.w = fmaxf((acc[3][c] - mu[3]) * rs[3] * g + b, 0.f);
      st4(ACT + (ch<<6) + (ag4 ^ ((ch&15)<<2)), v);
    }
  }

  #pragma unroll
  for (int r = 0; r < 4; ++r)
    #pragma unroll
    for (int c = 0; c < 8; ++c) acc[r][c] = 0.f;

  // layer 2: relu(GN(h1 @ W2) + actors) -> ACT
  gemm128c(ACT, W2 + (size_t)m*16384, WB0, WB1, acc, ag4, jg4, tid);
  gn_reduce(acc, PS1, PS2, MEAN, RSTD, ag4, jg, tid);
  {
    float mu[4], rs[4];
    #pragma unroll
    for (int r = 0; r < 4; ++r) { mu[r] = MEAN[ag4+r]; rs[r] = RSTD[ag4+r]; }
    #pragma unroll
    for (int c = 0; c < 8; ++c) {
      int ch = (c < 4) ? (jg4 + c) : (64 + jg4 + (c - 4));
      float g = g2v[m*128 + ch], b = b2v[m*128 + ch];
      float4 a = ld4(ACTORS + (ch<<6) + (ag4 ^ ((ch&15)<<2)));
      float4 v;
      v.x = fmaxf((acc[0][c] - mu[0]) * rs[0] * g + b + a.x, 0.f);
      v.y = fmaxf((acc[1][c] - mu[1]) * rs[1] * g + b + a.y, 0.f);
      v.z = fmaxf((acc[2][c] - mu[2]) * rs[2] * g + b + a.z, 0.f);
      v.w = fmaxf((acc[3][c] - mu[3]) * rs[3] * g + b + a.w, 0.f);
      st4(ACT + (ch<<6) + (ag4 ^ ((ch&15)<<2)), v);
    }
  }

  // output layer: h @ Wo + bo + ctr
  float acc2[4][4];
  #pragma unroll
  for (int r = 0; r < 4; ++r)
    #pragma unroll
    for (int c = 0; c < 4; ++c) acc2[r][c] = 0.f;
  gemm128wo(ACT, Wo + (size_t)m*7680, WB0, WB1, acc2, ag4, jg4, tid);

  if (jg < 15) {
    float4 bo4 = ld4(bov + m*60 + jg4);
    #pragma unroll
    for (int r = 0; r < 4; ++r) {
      int n = n0 + ag4 + r;
      float2 cc = *reinterpret_cast<const float2*>(ctrs + 2*n);
      float4 v;
      v.x = acc2[r][0] + bo4.x + cc.x;
      v.y = acc2[r][1] + bo4.y + cc.y;
      v.z = acc2[r][2] + bo4.z + cc.x;
      v.w = acc2[r][3] + bo4.w + cc.y;
      st4(out_reg + (size_t)n*360 + m*60 + jg4, v);
    }
  }
}

// ---------------- Kernel B: AttDest + cls head -> unsorted cls ----------------
__global__ void __launch_bounds__(256) att_cls_kernel(
    const float* __restrict__ actors, const float* __restrict__ ctrs,
    const float* __restrict__ dW1, const float* __restrict__ db1,
    const float* __restrict__ dW2, const float* __restrict__ dg2, const float* __restrict__ db2,
    const float* __restrict__ aW, const float* __restrict__ aG, const float* __restrict__ aB,
    const float* __restrict__ cW1, const float* __restrict__ cg1, const float* __restrict__ cb1,
    const float* __restrict__ cW2, const float* __restrict__ cg2, const float* __restrict__ cb2,
    const float* __restrict__ cWo, const float* __restrict__ cbo,
    const float* __restrict__ reg, float* __restrict__ cls_out)
{
  __shared__ __align__(16) float ACT[8192];
  __shared__ __align__(16) float FEATS[8192];
  __shared__ __align__(16) float WB0[1024], WB1[1024];
  __shared__ float PS1[320], PS2[320], MEAN[64], RSTD[64], D0x[64], D0y[64];

  const int tid = threadIdx.x;
  const int jg = tid & 15, ag = tid >> 4;
  const int jg4 = jg*4, ag4 = ag*4;
  const int r0 = blockIdx.x * 64;

  // dist0 = ctr - reg_last
  if (tid < 64) {
    int rg = r0 + tid;
    int n = rg / 6, mm = rg - 6*n;
    size_t base = (size_t)n*360 + mm*60;
    float2 c2 = *reinterpret_cast<const float2*>(ctrs + 2*n);
    D0x[tid] = c2.x - reg[base + 58];
    D0y[tid] = c2.y - reg[base + 59];
  }
  // stage agts -> FEATS
  #pragma unroll
  for (int p = 0; p < 8; ++p) {
    int i = (p<<8) + tid;
    int r = i >> 5, c4 = (i & 31) << 2;
    int n = (r0 + r) / 6;
    float4 v = ld4(actors + (size_t)n*128 + c4);
    FEATS[((c4+0)<<6) + (r ^ ((((c4+0))&15)<<2))] = v.x;
    FEATS[((c4+1)<<6) + (r ^ ((((c4+1))&15)<<2))] = v.y;
    FEATS[((c4+2)<<6) + (r ^ ((((c4+2))&15)<<2))] = v.z;
    FEATS[((c4+3)<<6) + (r ^ ((((c4+3))&15)<<2))] = v.w;
  }
  __syncthreads();

  // dist1 = relu(dist0 @ dW1 + db1) -> ACT
  {
    float dx[4], dy[4];
    #pragma unroll
    for (int r = 0; r < 4; ++r) { dx[r] = D0x[ag4+r]; dy[r] = D0y[ag4+r]; }
    #pragma unroll
    for (int c = 0; c < 8; ++c) {
      int ch = (c < 4) ? (jg4 + c) : (64 + jg4 + (c - 4));
      float w1 = dW1[ch], w2 = dW1[128 + ch], bb = db1[ch];
      float4 v;
      v.x = fmaxf(fmaf(dx[0], w1, fmaf(dy[0], w2, bb)), 0.f);
      v.y = fmaxf(fmaf(dx[1], w1, fmaf(dy[1], w2, bb)), 0.f);
      v.z = fmaxf(fmaf(dx[2], w1, fmaf(dy[2], w2, bb)), 0.f);
      v.w = fmaxf(fmaf(dx[3], w1, fmaf(dy[3], w2, bb)), 0.f);
      st4(ACT + (ch<<6) + (ag4 ^ ((ch&15)<<2)), v);
    }
  }

  float acc[4][8];
  #pragma unroll
  for (int r = 0; r < 4; ++r)
    #pragma unroll
    for (int c = 0; c < 8; ++c) acc[r][c] = 0.f;

  // phase 2: dist2 = relu(GN(dist1 @ dW2)) -> ACT
  gemm128c(ACT, dW2, WB0, WB1, acc, ag4, jg4, tid);
  gn_reduce(acc, PS1, PS2, MEAN, RSTD, ag4, jg, tid);
  {
    float mu[4], rs[4];
    #pragma unroll
    for (int r = 0; r < 4; ++r) { mu[r] = MEAN[ag4+r]; rs[r] = RSTD[ag4+r]; }
    #pragma unroll
    for (int c = 0; c < 8; ++c) {
      int ch = (c < 4) ? (jg4 + c) : (64 + jg4 + (c - 4));
      float g = dg2[ch], b = db2[ch];
      float4 v;
      v.x = fmaxf((acc[0][c] - mu[0]) * rs[0] * g + b, 0.f);
      v.y = fmaxf((acc[1][c] - mu[1]) * rs[1] * g + b, 0.f);
      v.z = fmaxf((acc[2][c] - mu[2]) * rs[2] * g + b, 0.f);
      v.w = fmaxf((acc[3][c] - mu[3]) * rs[3] * g + b, 0.f);
      st4(ACT + (ch<<6) + (ag4 ^ ((ch&15)<<2)), v);
    }
  }

  // phase 3: feats = relu(GN(dist2 @ aW_lo + agts @ aW_hi)) -> ACT, FEATS
  #pragma unroll
  for (int r = 0; r < 4; ++r)
    #pragma unroll
    for (int c = 0; c < 8; ++c) acc[r][c] = 0.f;
  gemm128c(ACT,   aW,            WB0, WB1, acc, ag4, jg4, tid);
  gemm128c(FEATS, aW + 128*128,  WB0, WB1, acc, ag4, jg4, tid);
  gn_reduce(acc, PS1, PS2, MEAN, RSTD, ag4, jg, tid);
  {
    float mu[4], rs[4];
    #pragma unroll
    for (int r = 0; r < 4; ++r) { mu[r] = MEAN[ag4+r]; rs[r] = RSTD[ag4+r]; }
    #pragma unroll
    for (int c = 0; c < 8; ++c) {
      int ch = (c < 4) ? (jg4 + c) : (64 + jg4 + (c - 4));
      float g = aG[ch], b = aB[ch];
      float4 v;
      v.x = fmaxf((acc[0][c] - mu[0]) * rs[0] * g + b, 0.f);
      v.y = fmaxf((acc[1][c] - mu[1]) * rs[1] * g + b, 0.f);
      v.z = fmaxf((acc[2][c] - mu[2]) * rs[2] * g + b, 0.f);
      v.w = fmaxf((acc[3][c] - mu[3]) * rs[3] * g + b, 0.f);
      st4(ACT   + (ch<<6) + (ag4 ^ ((ch&15)<<2)), v);
      st4(FEATS + (ch<<6) + (ag4 ^ ((ch&15)<<2)), v);
    }
  }

  // phase 4: c1 = relu(GN(feats @ cls_W1)) -> ACT
  #pragma unroll
  for (int r = 0; r < 4; ++r)
    #pragma unroll
    for (int c = 0; c < 8; ++c) acc[r][c] = 0.f;
  gemm128c(ACT, cW1, WB0, WB1, acc, ag4, jg4, tid);
  gn_reduce(acc, PS1, PS2, MEAN, RSTD, ag4, jg, tid);
  {
    float mu[4], rs[4];
    #pragma unroll
    for (int r = 0; r < 4; ++r) { mu[r] = MEAN[ag4+r]; rs[r] = RSTD[ag4+r]; }
    #pragma unroll
    for (int c = 0; c < 8; ++c) {
      int ch = (c < 4) ? (jg4 + c) : (64 + jg4 + (c - 4));
      float g = cg1[ch], b = cb1[ch];
      float4 v;
      v.x = fmaxf((acc[0][c] - mu[0]) * rs[0] * g + b, 0.f);
      v.y = fmaxf((acc[1][c] - mu[1]) * rs[1] * g + b, 0.f);
      v.z = fmaxf((acc[2][c] - mu[2]) * rs[2] * g + b, 0.f);
      v.w = fmaxf((acc[3][c] - mu[3]) * rs[3] * g + b, 0.f);
      st4(ACT + (ch<<6) + (ag4 ^ ((ch&15)<<2)), v);
    }
  }

  // phase 5: c2 = GN(c1 @ cls_W2); c = relu(c2 + feats); cls = c @ cls_Wo + bo
  #pragma unroll
  for (int r = 0; r < 4; ++r)
    #pragma unroll
    for (int c = 0; c < 8; ++c) acc[r][c] = 0.f;
  gemm128c(ACT, cW2, WB0, WB1, acc, ag4, jg4, tid);
  gn_reduce(acc, PS1, PS2, MEAN, RSTD, ag4, jg, tid);
  {
    float mu[4], rs[4], p[4] = {0.f, 0.f, 0.f, 0.f};
    #pragma unroll
    for (int r = 0; r < 4; ++r) { mu[r] = MEAN[ag4+r]; rs[r] = RSTD[ag4+r]; }
    #pragma unroll
    for (int c = 0; c < 8; ++c) {
      int ch = (c < 4) ? (jg4 + c) : (64 + jg4 + (c - 4));
      float g = cg2[ch], b = cb2[ch], wo = cWo[ch];
      float4 f = ld4(FEATS + (ch<<6) + (ag4 ^ ((ch&15)<<2)));
      p[0] = fmaf(fmaxf((acc[0][c] - mu[0]) * rs[0] * g + b + f.x, 0.f), wo, p[0]);
      p[1] = fmaf(fmaxf((acc[1][c] - mu[1]) * rs[1] * g + b + f.y, 0.f), wo, p[1]);
      p[2] = fmaf(fmaxf((acc[2][c] - mu[2]) * rs[2] * g + b + f.z, 0.f), wo, p[2]);
      p[3] = fmaf(fmaxf((acc[3][c] - mu[3]) * rs[3] * g + b + f.w, 0.f), wo, p[3]);
    }
    #pragma unroll
    for (int r = 0; r < 4; ++r) {
      float s = p[r];
      s += __shfl_xor(s, 1, 64);
      s += __shfl_xor(s, 2, 64);
      PS1[(ag4+r)*5 + (jg>>2)] = s;
    }
  }
  __syncthreads();
  if (tid < 64) {
    float s = 0.f;
    #pragma unroll
    for (int j = 0; j < 4; ++j) s += PS1[tid*5 + j];
    cls_out[r0 + tid] = s + cbo[0];
  }
}

// ---------------- Kernel C: per-actor stable descending sort + permute ----------------
__global__ void __launch_bounds__(256) sort_kernel(float* __restrict__ out)
{
  __shared__ float RL[64*360];
  __shared__ float CL[64*6];
  __shared__ float CS[64*6];
  __shared__ int   ORD[64*6];

  const int tid = threadIdx.x;
  const int n0 = blockIdx.x * 64;
  float* regp = out + CLS_SZ;

  for (int i = tid; i < 64*360; i += 256) RL[i] = regp[(size_t)n0*360 + i];
  for (int i = tid; i < 384; i += 256)    CL[i] = out[n0*6 + i];
  __syncthreads();

  if (tid < 64) {
    float v[6];
    #pragma unroll
    for (int m2 = 0; m2 < 6; ++m2) v[m2] = CL[tid*6 + m2];
    int used = 0;
    for (int j = 0; j < 6; ++j) {
      int best = -1; float bv = 0.f;
      for (int m2 = 0; m2 < 6; ++m2) {
        if (used & (1 << m2)) continue;
        if (best < 0 || v[m2] > bv) { best = m2; bv = v[m2]; }  // stable: strict >
      }
      used |= (1 << best);
      ORD[tid*6 + j] = best;
      CS[tid*6 + j] = bv;
    }
  }
  __syncthreads();

  for (int i = tid; i < 384; i += 256) out[n0*6 + i] = CS[i];
  for (int i = tid; i < 64*360; i += 256) {
    int rl = i / 360, rem = i - rl*360;
    int slot = rem / 60, j = rem - slot*60;
    out[CLS_SZ + (size_t)n0*360 + i] = RL[rl*360 + ORD[rl*6 + slot]*60 + j];
  }
}

extern "C" void kernel_launch(void* const* d_in, const int* in_sizes, int n_in,
                              void* d_out, int out_size, void* d_ws, size_t ws_size,
                              hipStream_t stream)
{
  (void)in_sizes; (void)n_in; (void)out_size; (void)d_ws; (void)ws_size;
  const float* actors = (const float*)d_in[0];
  const float* ctrs   = (const float*)d_in[1];
  // d_in[2] = actor_idcs (identity partition; unused by the math)
  const float* pW1 = (const float*)d_in[3];
  const float* pg1 = (const float*)d_in[4];
  const float* pb1 = (const float*)d_in[5];
  const float* pW2 = (const float*)d_in[6];
  const float* pg2 = (const float*)d_in[7];
  const float* pb2 = (const float*)d_in[8];
  const float* pWo = (const float*)d_in[9];
  const float* pbo = (const float*)d_in[10];
  const float* cW1 = (const float*)d_in[11];
  const float* cg1 = (const float*)d_in[12];
  const float* cb1 = (const float*)d_in[13];
  const float* cW2 = (const float*)d_in[14];
  const float* cg2 = (const float*)d_in[15];
  const float* cb2 = (const float*)d_in[16];
  const float* cWo = (const float*)d_in[17];
  const float* cbo = (const float*)d_in[18];
  const float* dW1 = (const float*)d_in[19];
  const float* db1 = (const float*)d_in[20];
  const float* dW2 = (const float*)d_in[21];
  const float* dg2 = (const float*)d_in[22];
  const float* db2 = (const float*)d_in[23];
  const float* aW  = (const float*)d_in[24];
  const float* aG  = (const float*)d_in[25];
  const float* aB  = (const float*)d_in[26];

  float* out = (float*)d_out;
  float* out_reg = out + CLS_SZ;

  dim3 gA(512, 6);
  pred_kernel<<<gA, 256, 0, stream>>>(actors, ctrs, pW1, pg1, pb1, pW2, pg2, pb2,
                                      pWo, pbo, out_reg);
  att_cls_kernel<<<3072, 256, 0, stream>>>(actors, ctrs,
                                           dW1, db1, dW2, dg2, db2,
                                           aW, aG, aB,
                                           cW1, cg1, cb1, cW2, cg2, cb2, cWo, cbo,
                                           out_reg, out);
  sort_kernel<<<512, 256, 0, stream>>>(out);
}